// Round 4
// baseline (144.815 us; speedup 1.0000x reference)
//
#include <hip/hip_runtime.h>
#include <hip/hip_bf16.h>
#include <stdint.h>

#define SEQ  256
#define PD   128

typedef short bf16x8 __attribute__((ext_vector_type(8)));
typedef float f32x4  __attribute__((ext_vector_type(4)));
typedef float f32x16 __attribute__((ext_vector_type(16)));
typedef short s16x4  __attribute__((ext_vector_type(4)));

__device__ __forceinline__ short f2bf(float x) {
    union { float f; uint32_t u; } v; v.f = x;
    uint32_t r = v.u + 0x7FFFu + ((v.u >> 16) & 1u);   // RNE
    return (short)(r >> 16);
}

__device__ __forceinline__ void gld16(const void* g, void* l) {
    __builtin_amdgcn_global_load_lds(
        (const __attribute__((address_space(1))) void*)g,
        (__attribute__((address_space(3))) void*)l, 16, 0, 0);
}

// ============ k_prep: pack weights (validated round 2) ============
__global__ __launch_bounds__(256) void k_prep(const float* __restrict__ w1,
                                              const float* __restrict__ w2,
                                              const float* __restrict__ w3,
                                              short* __restrict__ w12t,
                                              short* __restrict__ w3p) {
    int id = blockIdx.x * 256 + threadIdx.x;           // 18432 total
    if (id < 2048) {
        int col = id >> 5, cp = id & 31;
        int c = cp ^ (col & 7);
        bf16x8 o;
        #pragma unroll
        for (int e = 0; e < 8; ++e) {
            int k = c * 8 + e;
            float v = (col < 32) ? w2[k * 32 + col] : w1[k * 32 + (col - 32)];
            o[e] = f2bf(v);
        }
        *(bf16x8*)(w12t + id * 8) = o;
    } else {
        int id2 = id - 2048;                           // 0..16383
        int pg = id2 >> 12, ks = (id2 >> 6) & 63, l2 = id2 & 63;
        bf16x8 o;
        #pragma unroll
        for (int e = 0; e < 8; ++e) {
            int k = ks * 16 + (l2 >> 5) * 8 + e;
            int p = pg * 32 + (l2 & 31);
            o[e] = f2bf(w3[k * 128 + p]);
        }
        *(bf16x8*)(w3p + id2 * 8) = o;
    }
}

// ============ k_fused: LayerNorm + both projections (validated round 2) ============
__global__ __launch_bounds__(256) void k_fused(const float* __restrict__ msa,
                                               const float* __restrict__ nw,
                                               const float* __restrict__ nb_,
                                               const float* __restrict__ b1,
                                               const float* __restrict__ b2,
                                               const short* __restrict__ w12t,
                                               short* __restrict__ pa,
                                               short* __restrict__ pb) {
    __shared__ short smem[32768];                      // 64 KB
    int i = blockIdx.x, nbk = blockIdx.y;
    int t = threadIdx.x, l = t & 63, w = t >> 6;

    #pragma unroll
    for (int it = 0; it < 8; ++it) {
        int ci = it * 256 + t;
        gld16(w12t + (size_t)ci * 8, smem + (it * 256 + (t & ~63)) * 8);
    }
    float4 x[16];
    const float* basep = msa + ((size_t)(nbk * 64 + w * 16) * SEQ + i) * 256 + l * 4;
    #pragma unroll
    for (int j = 0; j < 16; ++j)
        x[j] = *(const float4*)(basep + (size_t)j * SEQ * 256);
    float4 wv = *(const float4*)(nw + l * 4);
    float4 bv = *(const float4*)(nb_ + l * 4);
    #pragma unroll
    for (int j = 0; j < 16; ++j) {
        float s = x[j].x + x[j].y + x[j].z + x[j].w;
        #pragma unroll
        for (int o = 32; o > 0; o >>= 1) s += __shfl_xor(s, o, 64);
        float mu = s * (1.0f / 256.0f);
        float dx = x[j].x - mu, dy = x[j].y - mu, dz = x[j].z - mu, dw = x[j].w - mu;
        float sq = dx * dx + dy * dy + dz * dz + dw * dw;
        #pragma unroll
        for (int o = 32; o > 0; o >>= 1) sq += __shfl_xor(sq, o, 64);
        float rs = rsqrtf(sq * (1.0f / 256.0f) + 1e-5f);
        s16x4 o4;
        o4[0] = f2bf(dx * rs * wv.x + bv.x);
        o4[1] = f2bf(dy * rs * wv.y + bv.y);
        o4[2] = f2bf(dz * rs * wv.z + bv.z);
        o4[3] = f2bf(dw * rs * wv.w + bv.w);
        int row = w * 16 + j;
        *(s16x4*)((char*)smem + 32768 + row * 512 + (((l >> 1) ^ (row & 7)) * 16) + (l & 1) * 8) = o4;
    }
    __syncthreads();
    int lr = l & 15, lk = l >> 4;
    f32x4 acc[4] = {};
    #pragma unroll
    for (int ks = 0; ks < 8; ++ks) {
        int c = ks * 4 + lk;
        int xr = w * 16 + lr;
        bf16x8 xf = *(bf16x8*)((char*)smem + 32768 + xr * 512 + ((c ^ (xr & 7)) * 16));
        #pragma unroll
        for (int af = 0; af < 4; ++af) {
            int rw = af * 16 + lr;
            bf16x8 wf = *(bf16x8*)((char*)smem + rw * 512 + ((c ^ (rw & 7)) * 16));
            acc[af] = __builtin_amdgcn_mfma_f32_16x16x32_bf16(wf, xf, acc[af], 0, 0, 0);
        }
    }
    int nglob = nbk * 64 + w * 16 + lr;
    #pragma unroll
    for (int af = 0; af < 4; ++af) {
        #pragma unroll
        for (int r = 0; r < 4; ++r) {
            int cc = af * 16 + lk * 4 + r;
            float bias = (cc < 32) ? b2[cc] : b1[cc - 32];
            short v = f2bf(acc[af][r] + bias);
            if (cc < 32) pa[(size_t)(i * 32 + cc) * 128 + nglob] = v;
            else         pb[(size_t)(i * 32 + (cc - 32)) * 128 + nglob] = v;
        }
    }
}

// ============ k_outer v3: 256x256 tile, 32x32x16 GEMM1, 16-wave GEMM2 ============
// LDS 128KB. Phase A: As/Bs per K-half h: [h*64KB): As 32KB | Bs 32KB, rows of 64
// shorts (8 chunks of 16B, slot c' = c ^ (row&7)). Phase B: A2 [64 pairs][2KB]:
// chunk q stored at q' = q ^ (pair&7) ^ ((q>>3)&7). Phase C: f32 scratch 96KB.
__global__ __launch_bounds__(1024) void k_outer(const short* __restrict__ pa,
                                                const short* __restrict__ pb,
                                                const short* __restrict__ w3p,
                                                const float* __restrict__ b3,
                                                float* __restrict__ out) {
    __shared__ short smem[65536];                      // 128 KB
    int t = threadIdx.x, l = t & 63, w = t >> 6;
    int lin = blockIdx.x;                              // 1024 blocks, XCD-bijective
    int swz = (lin & 7) * 128 + (lin >> 3);
    int bi = swz >> 5, bj = swz & 31;

    // ---- stage As/Bs: it 0..3 -> K-half0, it 4..7 -> K-half1 ----
    const short* srcA = pa + (size_t)bi * 256 * 128;
    const short* srcB = pb + (size_t)bj * 256 * 128;
    #pragma unroll
    for (int it = 0; it < 8; ++it) {
        int half = it >> 2, sub = it & 3;
        int buf = sub >> 1;                            // 0=A 1=B
        int row = (sub & 1) * 128 + (t >> 3);
        int c1  = t & 7;                               // LDS chunk slot
        int gch = (c1 ^ (row & 7)) + half * 8;         // global chunk 0..15
        const short* g = (buf ? srcB : srcA) + (size_t)row * 128 + gch * 8;
        int row0 = (sub & 1) * 128 + ((t & ~63) >> 3);
        gld16(g, smem + half * 32768 + buf * 16384 + row0 * 64);
    }
    // half0 ready: wait oldest 4 loads, barrier
    asm volatile("s_waitcnt vmcnt(4)" ::: "memory");
    __builtin_amdgcn_sched_barrier(0);
    __builtin_amdgcn_s_barrier();
    __builtin_amdgcn_sched_barrier(0);

    // ---- GEMM1: wave (wm,wn) owns 64x64; 2x2 frags of 32x32; D[n][m] via mfma(B,A) ----
    int wm = w & 3, wn = w >> 2;
    int l31 = l & 31, lh = l >> 5;
    f32x16 acc1[2][2] = {};                            // [fn][fm]
    #pragma unroll
    for (int ks2 = 0; ks2 < 4; ++ks2) {                // K-half0
        int g = ks2 * 2 + lh, half = g >> 3, c = g & 7;
        bf16x8 af[2], bfr[2];
        #pragma unroll
        for (int fm = 0; fm < 2; ++fm) {
            int row = wm * 64 + fm * 32 + l31;
            af[fm] = *(bf16x8*)(smem + half * 32768 + row * 64 + (c ^ (row & 7)) * 8);
        }
        #pragma unroll
        for (int fn = 0; fn < 2; ++fn) {
            int row = wn * 64 + fn * 32 + l31;
            bfr[fn] = *(bf16x8*)(smem + half * 32768 + 16384 + row * 64 + (c ^ (row & 7)) * 8);
        }
        __builtin_amdgcn_s_setprio(1);
        #pragma unroll
        for (int fn = 0; fn < 2; ++fn)
            #pragma unroll
            for (int fm = 0; fm < 2; ++fm)
                acc1[fn][fm] = __builtin_amdgcn_mfma_f32_32x32x16_bf16(bfr[fn], af[fm], acc1[fn][fm], 0, 0, 0);
        __builtin_amdgcn_s_setprio(0);
    }
    __syncthreads();                                   // drains vmcnt(0): half1 landed
    #pragma unroll
    for (int ks2 = 4; ks2 < 8; ++ks2) {                // K-half1
        int g = ks2 * 2 + lh, half = g >> 3, c = g & 7;
        bf16x8 af[2], bfr[2];
        #pragma unroll
        for (int fm = 0; fm < 2; ++fm) {
            int row = wm * 64 + fm * 32 + l31;
            af[fm] = *(bf16x8*)(smem + half * 32768 + row * 64 + (c ^ (row & 7)) * 8);
        }
        #pragma unroll
        for (int fn = 0; fn < 2; ++fn) {
            int row = wn * 64 + fn * 32 + l31;
            bfr[fn] = *(bf16x8*)(smem + half * 32768 + 16384 + row * 64 + (c ^ (row & 7)) * 8);
        }
        __builtin_amdgcn_s_setprio(1);
        #pragma unroll
        for (int fn = 0; fn < 2; ++fn)
            #pragma unroll
            for (int fm = 0; fm < 2; ++fm)
                acc1[fn][fm] = __builtin_amdgcn_mfma_f32_32x32x16_bf16(bfr[fn], af[fm], acc1[fn][fm], 0, 0, 0);
        __builtin_amdgcn_s_setprio(0);
    }
    __syncthreads();                                   // all GEMM1 reads done; As/Bs now dead

    // ---- repack acc1 -> A2. lane: a = l31, pair uniform per frag ----
    const float inv_n = 1.0f / 128.0f;
    #pragma unroll
    for (int fn = 0; fn < 2; ++fn) {
        #pragma unroll
        for (int fm = 0; fm < 2; ++fm) {
            int pair = (wm * 2 + fm) * 8 + wn * 2 + fn;
            #pragma unroll
            for (int g = 0; g < 4; ++g) {
                int q  = l31 * 4 + g;
                int qp = q ^ (pair & 7) ^ ((q >> 3) & 7);
                s16x4 o;
                #pragma unroll
                for (int j = 0; j < 4; ++j) o[j] = f2bf(acc1[fn][fm][g * 4 + j] * inv_n);
                *(s16x4*)(smem + pair * 1024 + qp * 8 + lh * 4) = o;
            }
        }
    }
    __syncthreads();

    // ---- GEMM2: M=64 pairs, N=128, K=1024. wave = (pg = w&3, kh = w>>2) ----
    int pg = w & 3, kh = w >> 2;
    f32x16 acc2[2] = {};
    __builtin_amdgcn_s_setprio(1);
    #pragma unroll
    for (int ksi = 0; ksi < 16; ++ksi) {
        int ksg = kh * 16 + ksi;
        bf16x8 b2f = *(const bf16x8*)(w3p + ((size_t)(pg * 64 + ksg) * 64 + l) * 8);
        int qr  = ksg * 2 + lh;
        int sig = (ksg >> 2) & 7;
        #pragma unroll
        for (int mq = 0; mq < 2; ++mq) {
            int prow = mq * 32 + l31;
            int qp = qr ^ (prow & 7) ^ sig;
            bf16x8 a2 = *(bf16x8*)(smem + prow * 1024 + qp * 8);
            acc2[mq] = __builtin_amdgcn_mfma_f32_32x32x16_bf16(a2, b2f, acc2[mq], 0, 0, 0);
        }
    }
    __builtin_amdgcn_s_setprio(0);
    __syncthreads();                                   // A2 dead; scratch reuse

    // ---- 4-way K reduction ----
    float* scratch = (float*)smem;                     // 96KB used
    if (kh != 0) {
        int base = ((kh - 1) * 4 + pg) * 2;
        #pragma unroll
        for (int mq = 0; mq < 2; ++mq)
            #pragma unroll
            for (int r = 0; r < 16; ++r)
                scratch[((base + mq) * 16 + r) * 64 + l] = acc2[mq][r];
    }
    __syncthreads();
    if (kh == 0) {
        int p = pg * 32 + l31;
        float bias = b3[p];
        #pragma unroll
        for (int mq = 0; mq < 2; ++mq) {
            #pragma unroll
            for (int r = 0; r < 16; ++r) {
                float v = acc2[mq][r];
                #pragma unroll
                for (int kk = 0; kk < 3; ++kk)
                    v += scratch[(((kk * 4 + pg) * 2 + mq) * 16 + r) * 64 + l];
                int pair = mq * 32 + (r & 3) + 8 * (r >> 2) + 4 * lh;
                int oi = bi * 8 + (pair >> 3), oj = bj * 8 + (pair & 7);
                out[((size_t)(oi * 256 + oj)) * 128 + p] = v + bias;
            }
        }
    }
}

extern "C" void kernel_launch(void* const* d_in, const int* in_sizes, int n_in,
                              void* d_out, int out_size, void* d_ws, size_t ws_size,
                              hipStream_t stream) {
    const float* msa = (const float*)d_in[0];
    const float* nw  = (const float*)d_in[1];
    const float* nbv = (const float*)d_in[2];
    const float* w1  = (const float*)d_in[3];
    const float* b1  = (const float*)d_in[4];
    const float* w2  = (const float*)d_in[5];
    const float* b2  = (const float*)d_in[6];
    const float* w3  = (const float*)d_in[7];
    const float* b3  = (const float*)d_in[8];
    float* out = (float*)d_out;

    char* ws = (char*)d_ws;
    short* pa   = (short*)ws;                          // 2 MB   (8192 x 128 bf16)
    short* pb   = (short*)(ws + (2u << 20));           // 2 MB
    short* w3p  = (short*)(ws + (4u << 20));           // 256 KB
    short* w12t = (short*)(ws + (4u << 20) + (256u << 10)); // 32 KB

    k_prep <<<72, 256, 0, stream>>>(w1, w2, w3, w12t, w3p);
    k_fused<<<dim3(256, 2), 256, 0, stream>>>(msa, nw, nbv, b1, b2, w12t, pa, pb);
    k_outer<<<1024, 1024, 0, stream>>>(pa, pb, w3p, b3, out);
}

// Round 7
// 141.834 us; speedup vs baseline: 1.0210x; 1.0210x over previous
//
#include <hip/hip_runtime.h>
#include <hip/hip_bf16.h>
#include <stdint.h>

#define SEQ  256
#define PD   128

typedef short bf16x8 __attribute__((ext_vector_type(8)));
typedef float f32x4  __attribute__((ext_vector_type(4)));
typedef float f32x16 __attribute__((ext_vector_type(16)));
typedef short s16x4  __attribute__((ext_vector_type(4)));

__device__ __forceinline__ short f2bf(float x) {
    union { float f; uint32_t u; } v; v.f = x;
    uint32_t r = v.u + 0x7FFFu + ((v.u >> 16) & 1u);   // RNE
    return (short)(r >> 16);
}

__device__ __forceinline__ void gld16(const void* g, void* l) {
    __builtin_amdgcn_global_load_lds(
        (const __attribute__((address_space(1))) void*)g,
        (__attribute__((address_space(3))) void*)l, 16, 0, 0);
}

// ============ k_prep: pack weights (w3 pre-scaled by 1/n_seq) ============
__global__ __launch_bounds__(256) void k_prep(const float* __restrict__ w1,
                                              const float* __restrict__ w2,
                                              const float* __restrict__ w3,
                                              short* __restrict__ w12t,
                                              short* __restrict__ w3p) {
    int id = blockIdx.x * 256 + threadIdx.x;           // 18432 total
    if (id < 2048) {
        int col = id >> 5, cp = id & 31;
        int c = cp ^ (col & 7);
        bf16x8 o;
        #pragma unroll
        for (int e = 0; e < 8; ++e) {
            int k = c * 8 + e;
            float v = (col < 32) ? w2[k * 32 + col] : w1[k * 32 + (col - 32)];
            o[e] = f2bf(v);
        }
        *(bf16x8*)(w12t + id * 8) = o;
    } else {
        int id2 = id - 2048;                           // 0..16383
        int pg = id2 >> 12, ks = (id2 >> 6) & 63, l2 = id2 & 63;
        bf16x8 o;
        #pragma unroll
        for (int e = 0; e < 8; ++e) {
            int k = ks * 16 + (l2 >> 5) * 8 + e;
            int p = pg * 32 + (l2 & 31);
            o[e] = f2bf(w3[k * 128 + p] * 0.0078125f);  // fold 1/n_seq into w3
        }
        *(bf16x8*)(w3p + id2 * 8) = o;
    }
}

// ============ k_fused: LayerNorm + both projections (validated round 2) ============
__global__ __launch_bounds__(256) void k_fused(const float* __restrict__ msa,
                                               const float* __restrict__ nw,
                                               const float* __restrict__ nb_,
                                               const float* __restrict__ b1,
                                               const float* __restrict__ b2,
                                               const short* __restrict__ w12t,
                                               short* __restrict__ pa,
                                               short* __restrict__ pb) {
    __shared__ short smem[32768];                      // 64 KB
    int i = blockIdx.x, nbk = blockIdx.y;
    int t = threadIdx.x, l = t & 63, w = t >> 6;

    #pragma unroll
    for (int it = 0; it < 8; ++it) {
        int ci = it * 256 + t;
        gld16(w12t + (size_t)ci * 8, smem + (it * 256 + (t & ~63)) * 8);
    }
    float4 x[16];
    const float* basep = msa + ((size_t)(nbk * 64 + w * 16) * SEQ + i) * 256 + l * 4;
    #pragma unroll
    for (int j = 0; j < 16; ++j)
        x[j] = *(const float4*)(basep + (size_t)j * SEQ * 256);
    float4 wv = *(const float4*)(nw + l * 4);
    float4 bv = *(const float4*)(nb_ + l * 4);
    #pragma unroll
    for (int j = 0; j < 16; ++j) {
        float s = x[j].x + x[j].y + x[j].z + x[j].w;
        #pragma unroll
        for (int o = 32; o > 0; o >>= 1) s += __shfl_xor(s, o, 64);
        float mu = s * (1.0f / 256.0f);
        float dx = x[j].x - mu, dy = x[j].y - mu, dz = x[j].z - mu, dw = x[j].w - mu;
        float sq = dx * dx + dy * dy + dz * dz + dw * dw;
        #pragma unroll
        for (int o = 32; o > 0; o >>= 1) sq += __shfl_xor(sq, o, 64);
        float rs = rsqrtf(sq * (1.0f / 256.0f) + 1e-5f);
        s16x4 o4;
        o4[0] = f2bf(dx * rs * wv.x + bv.x);
        o4[1] = f2bf(dy * rs * wv.y + bv.y);
        o4[2] = f2bf(dz * rs * wv.z + bv.z);
        o4[3] = f2bf(dw * rs * wv.w + bv.w);
        int row = w * 16 + j;
        *(s16x4*)((char*)smem + 32768 + row * 512 + (((l >> 1) ^ (row & 7)) * 16) + (l & 1) * 8) = o4;
    }
    __syncthreads();
    int lr = l & 15, lk = l >> 4;
    f32x4 acc[4] = {};
    #pragma unroll
    for (int ks = 0; ks < 8; ++ks) {
        int c = ks * 4 + lk;
        int xr = w * 16 + lr;
        bf16x8 xf = *(bf16x8*)((char*)smem + 32768 + xr * 512 + ((c ^ (xr & 7)) * 16));
        #pragma unroll
        for (int af = 0; af < 4; ++af) {
            int rw = af * 16 + lr;
            bf16x8 wf = *(bf16x8*)((char*)smem + rw * 512 + ((c ^ (rw & 7)) * 16));
            acc[af] = __builtin_amdgcn_mfma_f32_16x16x32_bf16(wf, xf, acc[af], 0, 0, 0);
        }
    }
    int nglob = nbk * 64 + w * 16 + lr;
    #pragma unroll
    for (int af = 0; af < 4; ++af) {
        #pragma unroll
        for (int r = 0; r < 4; ++r) {
            int cc = af * 16 + lk * 4 + r;
            float bias = (cc < 32) ? b2[cc] : b1[cc - 32];
            short v = f2bf(acc[af][r] + bias);
            if (cc < 32) pa[(size_t)(i * 32 + cc) * 128 + nglob] = v;
            else         pb[(size_t)(i * 32 + (cc - 32)) * 128 + nglob] = v;
        }
    }
}

// ============ k_outer v4: pipelined GEMM1, reg-preloaded GEMM2 B ============
// LDS 128KB. Phase A: As/Bs per K-half h: [h*64KB): As 32KB | Bs 32KB, rows of 64
// shorts (8 chunks16B, slot c' = c^(row&7)). Phase B: A2 [64 pairs][2KB]:
// chunk q at q' = q ^ (pair&7) ^ ((q>>3)&7). Phase C: f32 scratch 96KB.
__global__ __launch_bounds__(1024) void k_outer(const short* __restrict__ pa,
                                                const short* __restrict__ pb,
                                                const short* __restrict__ w3p,
                                                const float* __restrict__ b3,
                                                float* __restrict__ out) {
    __shared__ short smem[65536];                      // 128 KB
    int t = threadIdx.x, l = t & 63, w = t >> 6;
    int lin = blockIdx.x;                              // 1024 blocks, XCD-bijective
    int swz = (lin & 7) * 128 + (lin >> 3);
    int bi = swz >> 5, bj = swz & 31;

    // ---- stage As/Bs: it 0..3 -> K-half0, it 4..7 -> K-half1 ----
    const short* srcA = pa + (size_t)bi * 256 * 128;
    const short* srcB = pb + (size_t)bj * 256 * 128;
    #pragma unroll
    for (int it = 0; it < 8; ++it) {
        int half = it >> 2, sub = it & 3;
        int buf = sub >> 1;                            // 0=A 1=B
        int row = (sub & 1) * 128 + (t >> 3);
        int c1  = t & 7;                               // LDS chunk slot
        int gch = (c1 ^ (row & 7)) + half * 8;         // global chunk 0..15
        const short* g = (buf ? srcB : srcA) + (size_t)row * 128 + gch * 8;
        int row0 = (sub & 1) * 128 + ((t & ~63) >> 3);
        gld16(g, smem + half * 32768 + buf * 16384 + row0 * 64);
    }
    asm volatile("s_waitcnt vmcnt(4)" ::: "memory");   // half0 landed
    __builtin_amdgcn_sched_barrier(0);
    __builtin_amdgcn_s_barrier();
    __builtin_amdgcn_sched_barrier(0);

    // ---- GEMM1: wave (wm,wn) owns 64x64; 2x2 frags of 32x32; D[n][m] via mfma(B,A) ----
    int wm = w & 3, wn = w >> 2;
    int l31 = l & 31, lh = l >> 5;
    f32x16 acc1[2][2] = {};                            // [fn][fm]

    auto loadf = [&](int ks2, bf16x8* af, bf16x8* bfr) {
        int g = ks2 * 2 + lh, half = g >> 3, c = g & 7;
        #pragma unroll
        for (int fm = 0; fm < 2; ++fm) {
            int row = wm * 64 + fm * 32 + l31;
            af[fm] = *(bf16x8*)(smem + half * 32768 + row * 64 + (c ^ (row & 7)) * 8);
        }
        #pragma unroll
        for (int fn = 0; fn < 2; ++fn) {
            int row = wn * 64 + fn * 32 + l31;
            bfr[fn] = *(bf16x8*)(smem + half * 32768 + 16384 + row * 64 + (c ^ (row & 7)) * 8);
        }
    };

    bf16x8 fra[2][2], frb[2][2];                       // double-buffered frags
    loadf(0, fra[0], frb[0]);
    #pragma unroll
    for (int ks2 = 0; ks2 < 4; ++ks2) {                // K-half0
        if (ks2 < 3) loadf(ks2 + 1, fra[(ks2 + 1) & 1], frb[(ks2 + 1) & 1]);
        __builtin_amdgcn_s_setprio(1);
        #pragma unroll
        for (int fn = 0; fn < 2; ++fn)
            #pragma unroll
            for (int fm = 0; fm < 2; ++fm)
                acc1[fn][fm] = __builtin_amdgcn_mfma_f32_32x32x16_bf16(
                    frb[ks2 & 1][fn], fra[ks2 & 1][fm], acc1[fn][fm], 0, 0, 0);
        __builtin_amdgcn_s_setprio(0);
    }
    __syncthreads();                                   // drains vmcnt(0): half1 landed
    loadf(4, fra[0], frb[0]);
    #pragma unroll
    for (int ks2 = 4; ks2 < 8; ++ks2) {                // K-half1
        if (ks2 < 7) loadf(ks2 + 1, fra[(ks2 + 1) & 1], frb[(ks2 + 1) & 1]);
        __builtin_amdgcn_s_setprio(1);
        #pragma unroll
        for (int fn = 0; fn < 2; ++fn)
            #pragma unroll
            for (int fm = 0; fm < 2; ++fm)
                acc1[fn][fm] = __builtin_amdgcn_mfma_f32_32x32x16_bf16(
                    frb[ks2 & 1][fn], fra[ks2 & 1][fm], acc1[fn][fm], 0, 0, 0);
        __builtin_amdgcn_s_setprio(0);
    }
    __syncthreads();                                   // As/Bs now dead

    // ---- GEMM2 B preload, batch 1 (overlaps repack) ----
    int pg = w & 3, kh = w >> 2;
    const short* wbase = w3p + ((size_t)(pg * 64 + kh * 16) * 64 + l) * 8;
    bf16x8 b2f[16];
    #pragma unroll
    for (int ksi = 0; ksi < 8; ++ksi)
        b2f[ksi] = *(const bf16x8*)(wbase + ksi * 512);

    // ---- repack acc1 -> A2 (v_cvt_pk_bf16_f32, scale pre-folded into w3p) ----
    #pragma unroll
    for (int fn = 0; fn < 2; ++fn) {
        #pragma unroll
        for (int fm = 0; fm < 2; ++fm) {
            int pair = (wm * 2 + fm) * 8 + wn * 2 + fn;
            #pragma unroll
            for (int g = 0; g < 4; ++g) {
                int q  = l31 * 4 + g;
                int qp = q ^ (pair & 7) ^ ((q >> 3) & 7);
                union { uint32_t u[2]; s16x4 v; } pk;
                asm("v_cvt_pk_bf16_f32 %0, %1, %2"
                    : "=v"(pk.u[0])
                    : "v"(acc1[fn][fm][g * 4 + 0]), "v"(acc1[fn][fm][g * 4 + 1]));
                asm("v_cvt_pk_bf16_f32 %0, %1, %2"
                    : "=v"(pk.u[1])
                    : "v"(acc1[fn][fm][g * 4 + 2]), "v"(acc1[fn][fm][g * 4 + 3]));
                *(s16x4*)(smem + pair * 1024 + qp * 8 + lh * 4) = pk.v;
            }
        }
    }
    __syncthreads();

    // ---- GEMM2 B preload, batch 2 ----
    #pragma unroll
    for (int ksi = 8; ksi < 16; ++ksi)
        b2f[ksi] = *(const bf16x8*)(wbase + ksi * 512);

    // ---- GEMM2: M=64 pairs, N=128, K=1024. wave = (pg, kh); B in registers ----
    f32x16 acc2[2] = {};
    __builtin_amdgcn_s_setprio(1);
    #pragma unroll
    for (int ksi = 0; ksi < 16; ++ksi) {
        int ksg = kh * 16 + ksi;
        int qr  = ksg * 2 + lh;
        int sig = (ksg >> 2) & 7;
        #pragma unroll
        for (int mq = 0; mq < 2; ++mq) {
            int prow = mq * 32 + l31;
            int qp = qr ^ (prow & 7) ^ sig;
            bf16x8 a2 = *(bf16x8*)(smem + prow * 1024 + qp * 8);
            acc2[mq] = __builtin_amdgcn_mfma_f32_32x32x16_bf16(a2, b2f[ksi], acc2[mq], 0, 0, 0);
        }
    }
    __builtin_amdgcn_s_setprio(0);
    __syncthreads();                                   // A2 dead; scratch reuse

    // ---- 4-way K reduction ----
    float* scratch = (float*)smem;                     // 96KB used
    if (kh != 0) {
        int base = ((kh - 1) * 4 + pg) * 2;
        #pragma unroll
        for (int mq = 0; mq < 2; ++mq)
            #pragma unroll
            for (int r = 0; r < 16; ++r)
                scratch[((base + mq) * 16 + r) * 64 + l] = acc2[mq][r];
    }
    __syncthreads();
    if (kh == 0) {
        int p = pg * 32 + l31;
        float bias = b3[p];
        #pragma unroll
        for (int mq = 0; mq < 2; ++mq) {
            #pragma unroll
            for (int r = 0; r < 16; ++r) {
                float v = acc2[mq][r];
                #pragma unroll
                for (int kk = 0; kk < 3; ++kk)
                    v += scratch[(((kk * 4 + pg) * 2 + mq) * 16 + r) * 64 + l];
                int pair = mq * 32 + (r & 3) + 8 * (r >> 2) + 4 * lh;
                int oi = bi * 8 + (pair >> 3), oj = bj * 8 + (pair & 7);
                out[((size_t)(oi * 256 + oj)) * 128 + p] = v + bias;
            }
        }
    }
}

extern "C" void kernel_launch(void* const* d_in, const int* in_sizes, int n_in,
                              void* d_out, int out_size, void* d_ws, size_t ws_size,
                              hipStream_t stream) {
    const float* msa = (const float*)d_in[0];
    const float* nw  = (const float*)d_in[1];
    const float* nbv = (const float*)d_in[2];
    const float* w1  = (const float*)d_in[3];
    const float* b1  = (const float*)d_in[4];
    const float* w2  = (const float*)d_in[5];
    const float* b2  = (const float*)d_in[6];
    const float* w3  = (const float*)d_in[7];
    const float* b3  = (const float*)d_in[8];
    float* out = (float*)d_out;

    char* ws = (char*)d_ws;
    short* pa   = (short*)ws;                          // 2 MB   (8192 x 128 bf16)
    short* pb   = (short*)(ws + (2u << 20));           // 2 MB
    short* w3p  = (short*)(ws + (4u << 20));           // 256 KB
    short* w12t = (short*)(ws + (4u << 20) + (256u << 10)); // 32 KB

    k_prep <<<72, 256, 0, stream>>>(w1, w2, w3, w12t, w3p);
    k_fused<<<dim3(256, 2), 256, 0, stream>>>(msa, nw, nbv, b1, b2, w12t, pa, pb);
    k_outer<<<1024, 1024, 0, stream>>>(pa, pb, w3p, b3, out);
}